// Round 7
// baseline (304.306 us; speedup 1.0000x reference)
//
#include <hip/hip_runtime.h>

#define B_ 8
#define T_ 4096
#define C_ 128
#define HS_ 64

typedef _Float16 f16;
typedef _Float16 f16x8 __attribute__((ext_vector_type(8)));
typedef _Float16 f16x4 __attribute__((ext_vector_type(4)));
typedef float f32x4 __attribute__((ext_vector_type(4)));

#define MFMA32(a, b, c) __builtin_amdgcn_mfma_f32_16x16x32_f16(a, b, c, 0, 0, 0)
#define MFMA16(a, b, c) __builtin_amdgcn_mfma_f32_16x16x16f16(a, b, c, 0, 0, 0)
#define MEMBAR() asm volatile("" ::: "memory")

// ---------------------------------------------------------------------------
// Prep: WT[j][c] f16 (j<64: Wq*1/sqrt(C); <128: Wk; <192: Wv), row-major
// [192][128]; plus additive mask bias f16 [B][T] (0 or -30000).
// ---------------------------------------------------------------------------
__global__ void k_prep(const float* __restrict__ Wq, const float* __restrict__ Wk,
                       const float* __restrict__ Wv, const int* __restrict__ msk,
                       f16* __restrict__ WT, f16* __restrict__ bias) {
    int idx = blockIdx.x * 256 + threadIdx.x;
    if (idx < 192 * C_) {
        int j = idx >> 7, c = idx & 127;
        const float* W = (j < 64) ? Wq : (j < 128 ? Wk : Wv);
        float v = W[c * HS_ + (j & 63)];
        if (j < 64) v *= 0.08838834764831845f;     // 1/sqrt(128), folded into q
        WT[idx] = (f16)v;
    } else {
        int e = idx - 192 * C_;
        if (e < B_ * T_) bias[e] = msk[e] ? (f16)0.0f : (f16)(-30000.0f);
    }
}

// ---------------------------------------------------------------------------
// QKV projection + RoPE.  OUT^T = WT · x^T via 16x16x32 MFMA.
// WT fragments double-buffered (static ping-pong), float2 trig loads.
// ---------------------------------------------------------------------------
__global__ __launch_bounds__(256, 2) void k_qkv(const float* __restrict__ x,
        const f16* __restrict__ WT, const float* __restrict__ fcos,
        const float* __restrict__ fsin, f16* __restrict__ Q,
        f16* __restrict__ K, f16* __restrict__ VT) {
    const int b = blockIdx.y;
    const int w = threadIdx.x >> 6, lane = threadIdx.x & 63;
    const int col = lane & 15, g = lane >> 4;
    const int t = blockIdx.x * 64 + w * 16 + col;

    f16x8 bx[4];
    const float* xrow = x + ((size_t)(b * T_ + t)) * C_;
#pragma unroll
    for (int cc = 0; cc < 4; ++cc) {
        float4 x0 = *(const float4*)(xrow + cc * 32 + g * 8);
        float4 x1 = *(const float4*)(xrow + cc * 32 + g * 8 + 4);
        f16x8 v;
        v[0] = (f16)x0.x; v[1] = (f16)x0.y; v[2] = (f16)x0.z; v[3] = (f16)x0.w;
        v[4] = (f16)x1.x; v[5] = (f16)x1.y; v[6] = (f16)x1.z; v[7] = (f16)x1.w;
        bx[cc] = v;
    }

    f16x8 wt[2][4];
#pragma unroll
    for (int cc = 0; cc < 4; ++cc)
        wt[0][cc] = *(const f16x8*)(WT + (size_t)(col)*C_ + cc * 32 + g * 8);

#pragma unroll
    for (int jt = 0; jt < 12; ++jt) {
        if (jt < 11) {
#pragma unroll
            for (int cc = 0; cc < 4; ++cc)
                wt[(jt + 1) & 1][cc] = *(const f16x8*)(WT + (size_t)((jt + 1) * 16 + col) * C_ + cc * 32 + g * 8);
        }
        float2 c2, s2;
        if (jt < 8) {
            const int i0 = (jt & 3) * 8 + g * 2;
            c2 = *(const float2*)(fcos + t * 32 + i0);
            s2 = *(const float2*)(fsin + t * 32 + i0);
        }
        MEMBAR();
        f32x4 acc = {0.f, 0.f, 0.f, 0.f};
#pragma unroll
        for (int cc = 0; cc < 4; ++cc) acc = MFMA32(wt[jt & 1][cc], bx[cc], acc);

        if (jt < 8) {
            const int hbase = (jt & 3) * 16 + g * 4;   // even head-dim base
            float o0 = acc[0] * c2.x - acc[1] * s2.x;
            float o1 = acc[0] * s2.x + acc[1] * c2.x;
            float o2 = acc[2] * c2.y - acc[3] * s2.y;
            float o3 = acc[2] * s2.y + acc[3] * c2.y;
            f16x4 st; st[0] = (f16)o0; st[1] = (f16)o1; st[2] = (f16)o2; st[3] = (f16)o3;
            f16* dst = (jt < 4 ? Q : K);
            *(f16x4*)(dst + ((size_t)(b * T_ + t)) * HS_ + hbase) = st;
        } else {
            const int dbase = (jt - 8) * 16 + g * 4;
#pragma unroll
            for (int r = 0; r < 4; ++r)
                VT[((size_t)(b * HS_ + dbase + r)) * T_ + t] = (f16)acc[r];
        }
    }
}

// ---------------------------------------------------------------------------
// Flash attention, KVBLK=64, register double-buffer, f16 additive mask bias.
// __launch_bounds__(512,2): grid supplies only 2 waves/SIMD, so let the
// allocator use up to 256 VGPR and keep both tile buffers live.
// Waves 0-3 -> q-tile x, waves 4-7 -> q-tile 63-x (balanced); 1 block/CU.
// ---------------------------------------------------------------------------
struct Tile {
    f16x8 k[8];     // 4 subtiles x 2
    f16x4 bias[4];  // additive mask bias, this lane's g*4 slice
    f16x4 v[16];    // [sub][mt]
};

__device__ __forceinline__ void load_tile(Tile& t_, int it, const f16* __restrict__ kb,
        const f16* __restrict__ brow, const f16* __restrict__ vb, int col, int g) {
    const int kv0 = it * 64;
#pragma unroll
    for (int sub = 0; sub < 4; ++sub) {
        const f16* krow = kb + (size_t)(kv0 + sub * 16 + col) * HS_;
        t_.k[sub * 2]     = *(const f16x8*)(krow + g * 8);
        t_.k[sub * 2 + 1] = *(const f16x8*)(krow + 32 + g * 8);
        t_.bias[sub] = *(const f16x4*)(brow + kv0 + sub * 16 + g * 4);
#pragma unroll
        for (int mt = 0; mt < 4; ++mt)
            t_.v[sub * 4 + mt] = *(const f16x4*)(vb + (size_t)(col + 16 * mt) * T_ + kv0 + sub * 16 + g * 4);
    }
}

__device__ __forceinline__ void compute_tile(const Tile& t_, int it, bool last,
        f16x8 bq0, f16x8 bq1, int qc, int g,
        float& m, float& lsum, f32x4& o0, f32x4& o1, f32x4& o2, f32x4& o3) {
    float sv[16];
#pragma unroll
    for (int sub = 0; sub < 4; ++sub) {
        f32x4 s = {0.f, 0.f, 0.f, 0.f};
        s = MFMA32(t_.k[sub * 2], bq0, s);
        s = MFMA32(t_.k[sub * 2 + 1], bq1, s);
        const int kbase = it * 64 + sub * 16 + g * 4;
        float b0 = (float)t_.bias[sub][0], b1 = (float)t_.bias[sub][1];
        float b2 = (float)t_.bias[sub][2], b3 = (float)t_.bias[sub][3];
        if (last) {
            b0 = (kbase + 0 <= qc) ? b0 : -1e30f;
            b1 = (kbase + 1 <= qc) ? b1 : -1e30f;
            b2 = (kbase + 2 <= qc) ? b2 : -1e30f;
            b3 = (kbase + 3 <= qc) ? b3 : -1e30f;
        }
        sv[sub * 4 + 0] = s.x + b0;
        sv[sub * 4 + 1] = s.y + b1;
        sv[sub * 4 + 2] = s.z + b2;
        sv[sub * 4 + 3] = s.w + b3;
    }
    float t0 = fmaxf(fmaxf(sv[0], sv[1]),   fmaxf(sv[2], sv[3]));
    float t1 = fmaxf(fmaxf(sv[4], sv[5]),   fmaxf(sv[6], sv[7]));
    float t2 = fmaxf(fmaxf(sv[8], sv[9]),   fmaxf(sv[10], sv[11]));
    float t3 = fmaxf(fmaxf(sv[12], sv[13]), fmaxf(sv[14], sv[15]));
    float tm = fmaxf(fmaxf(t0, t1), fmaxf(t2, t3));
    tm = fmaxf(tm, __shfl_xor(tm, 16));
    tm = fmaxf(tm, __shfl_xor(tm, 32));
    const float mn = fmaxf(m, tm);
    const float sc = __expf(m - mn);
#pragma unroll
    for (int i = 0; i < 16; ++i) sv[i] = __expf(sv[i] - mn);
    float a0 = (sv[0] + sv[1]) + (sv[2] + sv[3]);
    float a1 = (sv[4] + sv[5]) + (sv[6] + sv[7]);
    float a2 = (sv[8] + sv[9]) + (sv[10] + sv[11]);
    float a3 = (sv[12] + sv[13]) + (sv[14] + sv[15]);
    float ts = (a0 + a1) + (a2 + a3);
    ts += __shfl_xor(ts, 16);
    ts += __shfl_xor(ts, 32);
    lsum = lsum * sc + ts;
    m = mn;
    o0 *= sc; o1 *= sc; o2 *= sc; o3 *= sc;
#pragma unroll
    for (int sub = 0; sub < 4; ++sub) {
        f16x4 pf;
        pf[0] = (f16)sv[sub * 4 + 0]; pf[1] = (f16)sv[sub * 4 + 1];
        pf[2] = (f16)sv[sub * 4 + 2]; pf[3] = (f16)sv[sub * 4 + 3];
        o0 = MFMA16(t_.v[sub * 4 + 0], pf, o0);
        o1 = MFMA16(t_.v[sub * 4 + 1], pf, o1);
        o2 = MFMA16(t_.v[sub * 4 + 2], pf, o2);
        o3 = MFMA16(t_.v[sub * 4 + 3], pf, o3);
    }
}

__global__ __launch_bounds__(512, 2) void k_attn(const f16* __restrict__ Q,
        const f16* __restrict__ K, const f16* __restrict__ VT,
        const f16* __restrict__ bias, float* __restrict__ out) {
    const int b = blockIdx.y;
    const int w = threadIdx.x >> 6, lane = threadIdx.x & 63;
    const int col = lane & 15, g = lane >> 4;
    const int w4 = w & 3;
    const int tq = (w < 4) ? (int)blockIdx.x : (63 - (int)blockIdx.x);
    const int qc = tq * 64 + w4 * 16 + col;
    const int itLast = tq;   // wave-uniform, KVBLK=64

    const f16* qrow = Q + ((size_t)(b * T_ + qc)) * HS_;
    f16x8 bq0 = *(const f16x8*)(qrow + g * 8);
    f16x8 bq1 = *(const f16x8*)(qrow + 32 + g * 8);

    float m = -3.0e38f, lsum = 0.f;
    f32x4 o0 = {0,0,0,0}, o1 = {0,0,0,0}, o2 = {0,0,0,0}, o3 = {0,0,0,0};
    const f16* brow = bias + (size_t)b * T_;
    const f16* kb = K + (size_t)b * T_ * HS_;
    const f16* vb = VT + (size_t)b * HS_ * T_;

    Tile A, Bt;
    load_tile(A, 0, kb, brow, vb, col, g);
    int it = 0;
    for (; it + 2 <= itLast; it += 2) {
        load_tile(Bt, it + 1, kb, brow, vb, col, g);
        MEMBAR();
        compute_tile(A, it, false, bq0, bq1, qc, g, m, lsum, o0, o1, o2, o3);
        load_tile(A, it + 2, kb, brow, vb, col, g);
        MEMBAR();
        compute_tile(Bt, it + 1, false, bq0, bq1, qc, g, m, lsum, o0, o1, o2, o3);
    }
    if (it < itLast) {
        load_tile(Bt, it + 1, kb, brow, vb, col, g);
        MEMBAR();
        compute_tile(A, it, false, bq0, bq1, qc, g, m, lsum, o0, o1, o2, o3);
        compute_tile(Bt, it + 1, true, bq0, bq1, qc, g, m, lsum, o0, o1, o2, o3);
    } else {
        compute_tile(A, it, true, bq0, bq1, qc, g, m, lsum, o0, o1, o2, o3);
    }

    const float inv = 1.0f / lsum;
    float* orow = out + ((size_t)(b * T_ + qc)) * HS_;
    float4 u;
    u.x = o0.x * inv; u.y = o0.y * inv; u.z = o0.z * inv; u.w = o0.w * inv;
    *(float4*)(orow + 0  + g * 4) = u;
    u.x = o1.x * inv; u.y = o1.y * inv; u.z = o1.z * inv; u.w = o1.w * inv;
    *(float4*)(orow + 16 + g * 4) = u;
    u.x = o2.x * inv; u.y = o2.y * inv; u.z = o2.z * inv; u.w = o2.w * inv;
    *(float4*)(orow + 32 + g * 4) = u;
    u.x = o3.x * inv; u.y = o3.y * inv; u.z = o3.z * inv; u.w = o3.w * inv;
    *(float4*)(orow + 48 + g * 4) = u;
}

// ---------------------------------------------------------------------------
extern "C" void kernel_launch(void* const* d_in, const int* in_sizes, int n_in,
                              void* d_out, int out_size, void* d_ws, size_t ws_size,
                              hipStream_t stream) {
    const float* x    = (const float*)d_in[0];
    const float* Wq   = (const float*)d_in[1];
    const float* Wk   = (const float*)d_in[2];
    const float* Wv   = (const float*)d_in[3];
    const float* fcos = (const float*)d_in[4];
    const float* fsin = (const float*)d_in[5];
    const int*   msk  = (const int*)d_in[6];

    char* ws = (char*)d_ws;
    const size_t qkv_bytes = (size_t)B_ * T_ * HS_ * sizeof(f16);   // 4 MB each
    f16* WT   = (f16*)ws;                                // 48 KB
    f16* bias = (f16*)(ws + (48 << 10));                 // 64 KB
    f16* Q    = (f16*)(ws + (1 << 17));
    f16* K    = (f16*)(ws + (1 << 17) + qkv_bytes);
    f16* VT   = (f16*)(ws + (1 << 17) + 2 * qkv_bytes);

    k_prep<<<224, 256, 0, stream>>>(Wq, Wk, Wv, msk, WT, bias);
    dim3 g1(T_ / 64, B_);
    k_qkv<<<g1, 256, 0, stream>>>(x, WT, fcos, fsin, Q, K, VT);
    dim3 g2(32, B_);
    k_attn<<<g2, 512, 0, stream>>>(Q, K, VT, bias, (float*)d_out);
}

// Round 8
// 277.086 us; speedup vs baseline: 1.0982x; 1.0982x over previous
//
#include <hip/hip_runtime.h>

#define B_ 8
#define T_ 4096
#define C_ 128
#define HS_ 64

typedef _Float16 f16;
typedef _Float16 f16x8 __attribute__((ext_vector_type(8)));
typedef _Float16 f16x4 __attribute__((ext_vector_type(4)));
typedef float f32x4 __attribute__((ext_vector_type(4)));

#define MFMA32(a, b, c) __builtin_amdgcn_mfma_f32_16x16x32_f16(a, b, c, 0, 0, 0)
#define MFMA16(a, b, c) __builtin_amdgcn_mfma_f32_16x16x16f16(a, b, c, 0, 0, 0)

// ---------------------------------------------------------------------------
// Prep: WT[j][c] f16 (j<64: Wq*1/sqrt(C); <128: Wk; <192: Wv), row-major
// [192][128]; plus additive mask bias f16 [B][T] (0 or -30000).
// ---------------------------------------------------------------------------
__global__ void k_prep(const float* __restrict__ Wq, const float* __restrict__ Wk,
                       const float* __restrict__ Wv, const int* __restrict__ msk,
                       f16* __restrict__ WT, f16* __restrict__ bias) {
    int idx = blockIdx.x * 256 + threadIdx.x;
    if (idx < 192 * C_) {
        int j = idx >> 7, c = idx & 127;
        const float* W = (j < 64) ? Wq : (j < 128 ? Wk : Wv);
        float v = W[c * HS_ + (j & 63)];
        if (j < 64) v *= 0.08838834764831845f;     // 1/sqrt(128), folded into q
        WT[idx] = (f16)v;
    } else {
        int e = idx - 192 * C_;
        if (e < B_ * T_) bias[e] = msk[e] ? (f16)0.0f : (f16)(-30000.0f);
    }
}

// ---------------------------------------------------------------------------
// QKV projection + RoPE.  OUT^T = WT · x^T via 16x16x32 MFMA.
// jt-split across blocks (x&1): half 0 -> jt 0-5 (Q + K lo), half 1 ->
// jt 6-11 (K hi + V).  4 blocks/CU -> 4 waves/SIMD.
// ---------------------------------------------------------------------------
__global__ __launch_bounds__(256, 4) void k_qkv(const float* __restrict__ x,
        const f16* __restrict__ WT, const float* __restrict__ fcos,
        const float* __restrict__ fsin, f16* __restrict__ Q,
        f16* __restrict__ K, f16* __restrict__ VT) {
    const int b = blockIdx.y;
    const int tile64 = blockIdx.x >> 1, jh = blockIdx.x & 1;
    const int w = threadIdx.x >> 6, lane = threadIdx.x & 63;
    const int col = lane & 15, g = lane >> 4;
    const int t = tile64 * 64 + w * 16 + col;

    f16x8 bx[4];
    const float* xrow = x + ((size_t)(b * T_ + t)) * C_;
#pragma unroll
    for (int cc = 0; cc < 4; ++cc) {
        float4 x0 = *(const float4*)(xrow + cc * 32 + g * 8);
        float4 x1 = *(const float4*)(xrow + cc * 32 + g * 8 + 4);
        f16x8 v;
        v[0] = (f16)x0.x; v[1] = (f16)x0.y; v[2] = (f16)x0.z; v[3] = (f16)x0.w;
        v[4] = (f16)x1.x; v[5] = (f16)x1.y; v[6] = (f16)x1.z; v[7] = (f16)x1.w;
        bx[cc] = v;
    }

#pragma unroll
    for (int jj = 0; jj < 6; ++jj) {
        const int jt = jh * 6 + jj;
        f32x4 acc = {0.f, 0.f, 0.f, 0.f};
#pragma unroll
        for (int cc = 0; cc < 4; ++cc) {
            f16x8 aw = *(const f16x8*)(WT + (size_t)(jt * 16 + col) * C_ + cc * 32 + g * 8);
            acc = MFMA32(aw, bx[cc], acc);
        }
        if (jt < 8) {
            const int hbase = (jt & 3) * 16 + g * 4;   // even head-dim base
            const int i0 = hbase >> 1;
            float2 c2 = *(const float2*)(fcos + t * 32 + i0);
            float2 s2 = *(const float2*)(fsin + t * 32 + i0);
            float o0 = acc[0] * c2.x - acc[1] * s2.x;
            float o1 = acc[0] * s2.x + acc[1] * c2.x;
            float o2 = acc[2] * c2.y - acc[3] * s2.y;
            float o3 = acc[2] * s2.y + acc[3] * c2.y;
            f16x4 st; st[0] = (f16)o0; st[1] = (f16)o1; st[2] = (f16)o2; st[3] = (f16)o3;
            f16* dst = (jt < 4 ? Q : K);
            *(f16x4*)(dst + ((size_t)(b * T_ + t)) * HS_ + hbase) = st;
        } else {
            const int dbase = (jt - 8) * 16 + g * 4;
#pragma unroll
            for (int r = 0; r < 4; ++r)
                VT[((size_t)(b * HS_ + dbase + r)) * T_ + t] = (f16)acc[r];
        }
    }
}

// ---------------------------------------------------------------------------
// Flash attention, split-KV x2 for TLP.
// Block = 1024 thr = 16 waves = {q-tile x, q-tile 63-x} x {4 row-groups} x
// {2 kv-halves}.  Grid (32,B) = 256 blocks = 1/CU -> 4 waves/SIMD, balanced.
// KVBLK=32, single-buffered (latency hidden by wave TLP, not ILP).
// Halves merged via LDS (m, l, O) with one __syncthreads.
// ---------------------------------------------------------------------------
__device__ __forceinline__ void tile32(int it, bool last,
        const f16* __restrict__ kb, const f16* __restrict__ brow,
        const f16* __restrict__ vb, int col, int g, int qc,
        f16x8 bq0, f16x8 bq1,
        float& m, float& lsum, f32x4& o0, f32x4& o1, f32x4& o2, f32x4& o3) {
    const int kv0 = it * 32;
    float sv[8];
#pragma unroll
    for (int sub = 0; sub < 2; ++sub) {
        const f16* krow = kb + (size_t)(kv0 + sub * 16 + col) * HS_;
        f16x8 ak0 = *(const f16x8*)(krow + g * 8);
        f16x8 ak1 = *(const f16x8*)(krow + 32 + g * 8);
        f16x4 bias = *(const f16x4*)(brow + kv0 + sub * 16 + g * 4);
        f32x4 s = {0.f, 0.f, 0.f, 0.f};
        s = MFMA32(ak0, bq0, s);
        s = MFMA32(ak1, bq1, s);
        const int kbase = kv0 + sub * 16 + g * 4;
        float b0 = (float)bias[0], b1 = (float)bias[1];
        float b2 = (float)bias[2], b3 = (float)bias[3];
        if (last) {
            b0 = (kbase + 0 <= qc) ? b0 : -1e30f;
            b1 = (kbase + 1 <= qc) ? b1 : -1e30f;
            b2 = (kbase + 2 <= qc) ? b2 : -1e30f;
            b3 = (kbase + 3 <= qc) ? b3 : -1e30f;
        }
        sv[sub * 4 + 0] = s.x + b0;
        sv[sub * 4 + 1] = s.y + b1;
        sv[sub * 4 + 2] = s.z + b2;
        sv[sub * 4 + 3] = s.w + b3;
    }
    float t0 = fmaxf(fmaxf(sv[0], sv[1]), fmaxf(sv[2], sv[3]));
    float t1 = fmaxf(fmaxf(sv[4], sv[5]), fmaxf(sv[6], sv[7]));
    float tm = fmaxf(t0, t1);
    tm = fmaxf(tm, __shfl_xor(tm, 16));
    tm = fmaxf(tm, __shfl_xor(tm, 32));
    const float mn = fmaxf(m, tm);
    const float sc = __expf(m - mn);
#pragma unroll
    for (int i = 0; i < 8; ++i) sv[i] = __expf(sv[i] - mn);
    float ts = ((sv[0] + sv[1]) + (sv[2] + sv[3])) + ((sv[4] + sv[5]) + (sv[6] + sv[7]));
    ts += __shfl_xor(ts, 16);
    ts += __shfl_xor(ts, 32);
    lsum = lsum * sc + ts;
    m = mn;
    o0 *= sc; o1 *= sc; o2 *= sc; o3 *= sc;
#pragma unroll
    for (int sub = 0; sub < 2; ++sub) {
        f16x4 pf;
        pf[0] = (f16)sv[sub * 4 + 0]; pf[1] = (f16)sv[sub * 4 + 1];
        pf[2] = (f16)sv[sub * 4 + 2]; pf[3] = (f16)sv[sub * 4 + 3];
        const f16* vbase = vb + kv0 + sub * 16 + g * 4;
        o0 = MFMA16(*(const f16x4*)(vbase + (size_t)(col)      * T_), pf, o0);
        o1 = MFMA16(*(const f16x4*)(vbase + (size_t)(col + 16) * T_), pf, o1);
        o2 = MFMA16(*(const f16x4*)(vbase + (size_t)(col + 32) * T_), pf, o2);
        o3 = MFMA16(*(const f16x4*)(vbase + (size_t)(col + 48) * T_), pf, o3);
    }
}

__global__ __launch_bounds__(1024, 4) void k_attn(const f16* __restrict__ Q,
        const f16* __restrict__ K, const f16* __restrict__ VT,
        const f16* __restrict__ bias, float* __restrict__ out) {
    __shared__ float lds_o[8][64][17];
    __shared__ float lds_m[8][64];
    __shared__ float lds_l[8][64];

    const int b = blockIdx.y;
    const int w = threadIdx.x >> 6, lane = threadIdx.x & 63;
    const int col = lane & 15, g = lane >> 4;
    const int r = w & 3;               // row-group
    const int h = (w >> 2) & 1;        // kv half
    const int side = w >> 3;           // 0: q-tile x, 1: q-tile 63-x
    const int tq = side ? (63 - (int)blockIdx.x) : (int)blockIdx.x;
    const int qc = tq * 64 + r * 16 + col;
    const int slot = side * 4 + r;

    const f16* qrow = Q + ((size_t)(b * T_ + qc)) * HS_;
    f16x8 bq0 = *(const f16x8*)(qrow + g * 8);
    f16x8 bq1 = *(const f16x8*)(qrow + 32 + g * 8);

    float m = -3.0e38f, lsum = 0.f;
    f32x4 o0 = {0,0,0,0}, o1 = {0,0,0,0}, o2 = {0,0,0,0}, o3 = {0,0,0,0};
    const f16* brow = bias + (size_t)b * T_;
    const f16* kb = K + (size_t)b * T_ * HS_;
    const f16* vb = VT + (size_t)b * HS_ * T_;

    const int itW = (tq * 64 + r * 16 + 15) >> 5;   // last kv tile (inclusive)
    const int mid = (itW + 1) >> 1;
    const int start = h ? mid : 0;
    const int end   = h ? itW : (mid - 1);          // inclusive

    for (int it = start; it <= end; ++it)
        tile32(it, it == itW, kb, brow, vb, col, g, qc, bq0, bq1,
               m, lsum, o0, o1, o2, o3);

    // merge halves: h=1 publishes, h=0 combines + writes
    if (h) {
        lds_m[slot][lane] = m;
        lds_l[slot][lane] = lsum;
        float* p = lds_o[slot][lane];
        p[0] = o0.x;  p[1] = o0.y;  p[2] = o0.z;  p[3] = o0.w;
        p[4] = o1.x;  p[5] = o1.y;  p[6] = o1.z;  p[7] = o1.w;
        p[8] = o2.x;  p[9] = o2.y;  p[10] = o2.z; p[11] = o2.w;
        p[12] = o3.x; p[13] = o3.y; p[14] = o3.z; p[15] = o3.w;
    }
    __syncthreads();
    if (!h) {
        const float mB = lds_m[slot][lane];
        const float lB = lds_l[slot][lane];
        const float mn = fmaxf(m, mB);
        const float sA = __expf(m - mn), sB = __expf(mB - mn);
        const float inv = 1.0f / (lsum * sA + lB * sB);
        const float* p = lds_o[slot][lane];
        float* orow = out + ((size_t)(b * T_ + qc)) * HS_;
        float4 u;
        u.x = (o0.x * sA + p[0] * sB) * inv;  u.y = (o0.y * sA + p[1] * sB) * inv;
        u.z = (o0.z * sA + p[2] * sB) * inv;  u.w = (o0.w * sA + p[3] * sB) * inv;
        *(float4*)(orow + 0  + g * 4) = u;
        u.x = (o1.x * sA + p[4] * sB) * inv;  u.y = (o1.y * sA + p[5] * sB) * inv;
        u.z = (o1.z * sA + p[6] * sB) * inv;  u.w = (o1.w * sA + p[7] * sB) * inv;
        *(float4*)(orow + 16 + g * 4) = u;
        u.x = (o2.x * sA + p[8] * sB) * inv;  u.y = (o2.y * sA + p[9] * sB) * inv;
        u.z = (o2.z * sA + p[10] * sB) * inv; u.w = (o2.w * sA + p[11] * sB) * inv;
        *(float4*)(orow + 32 + g * 4) = u;
        u.x = (o3.x * sA + p[12] * sB) * inv; u.y = (o3.y * sA + p[13] * sB) * inv;
        u.z = (o3.z * sA + p[14] * sB) * inv; u.w = (o3.w * sA + p[15] * sB) * inv;
        *(float4*)(orow + 48 + g * 4) = u;
    }
}

// ---------------------------------------------------------------------------
extern "C" void kernel_launch(void* const* d_in, const int* in_sizes, int n_in,
                              void* d_out, int out_size, void* d_ws, size_t ws_size,
                              hipStream_t stream) {
    const float* x    = (const float*)d_in[0];
    const float* Wq   = (const float*)d_in[1];
    const float* Wk   = (const float*)d_in[2];
    const float* Wv   = (const float*)d_in[3];
    const float* fcos = (const float*)d_in[4];
    const float* fsin = (const float*)d_in[5];
    const int*   msk  = (const int*)d_in[6];

    char* ws = (char*)d_ws;
    const size_t qkv_bytes = (size_t)B_ * T_ * HS_ * sizeof(f16);   // 4 MB each
    f16* WT   = (f16*)ws;                                // 48 KB
    f16* bias = (f16*)(ws + (48 << 10));                 // 64 KB
    f16* Q    = (f16*)(ws + (1 << 17));
    f16* K    = (f16*)(ws + (1 << 17) + qkv_bytes);
    f16* VT   = (f16*)(ws + (1 << 17) + 2 * qkv_bytes);

    k_prep<<<224, 256, 0, stream>>>(Wq, Wk, Wv, msk, WT, bias);
    dim3 g1(T_ / 32, B_);
    k_qkv<<<g1, 256, 0, stream>>>(x, WT, fcos, fsin, Q, K, VT);
    dim3 g2(32, B_);
    k_attn<<<g2, 1024, 0, stream>>>(Q, K, VT, bias, (float*)d_out);
}

// Round 9
// 171.694 us; speedup vs baseline: 1.7724x; 1.6138x over previous
//
#include <hip/hip_runtime.h>

#define B_ 8
#define T_ 4096
#define C_ 128
#define HS_ 64
#define NT16 (T_ / 16)

typedef _Float16 f16;
typedef _Float16 f16x8 __attribute__((ext_vector_type(8)));
typedef _Float16 f16x4 __attribute__((ext_vector_type(4)));
typedef float f32x4 __attribute__((ext_vector_type(4)));

#define MFMA32(a, b, c) __builtin_amdgcn_mfma_f32_16x16x32_f16(a, b, c, 0, 0, 0)
#define MFMA16(a, b, c) __builtin_amdgcn_mfma_f32_16x16x16f16(a, b, c, 0, 0, 0)

// ---------------------------------------------------------------------------
// Fragment-major layouts (per [b][t16] block of 1024 f16 = 2 KB):
//  Q/K (QK-operand):  [h(2)][lane=g*16+col][8]   lane reads b128 = X[t0+col][h*32+g*8..+8]
//  V   (PV A-frag):   [mt(4)][lane=g*16+col][4]  lane reads b64  = V[16mt+col][t0+g*4..+4]
// Every k_attn load instruction covers a contiguous 512-1024B run.
// ---------------------------------------------------------------------------

__global__ void k_prep(const float* __restrict__ Wq, const float* __restrict__ Wk,
                       const float* __restrict__ Wv, const int* __restrict__ msk,
                       f16* __restrict__ WT, f16* __restrict__ bias) {
    int idx = blockIdx.x * 256 + threadIdx.x;
    if (idx < 192 * C_) {
        int j = idx >> 7, c = idx & 127;
        const float* W = (j < 64) ? Wq : (j < 128 ? Wk : Wv);
        float v = W[c * HS_ + (j & 63)];
        if (j < 64) v *= 0.08838834764831845f;     // 1/sqrt(128) folded into q
        WT[idx] = (f16)v;
    } else {
        int e = idx - 192 * C_;
        if (e < B_ * T_) bias[e] = msk[e] ? (f16)0.0f : (f16)(-30000.0f);
    }
}

// ---------------------------------------------------------------------------
// QKV projection + RoPE, storing fragment-major outputs.
// jt-split across blocks (x&1): half 0 -> jt 0-5, half 1 -> jt 6-11.
// ---------------------------------------------------------------------------
__global__ __launch_bounds__(256, 2) void k_qkv(const float* __restrict__ x,
        const f16* __restrict__ WT, const float* __restrict__ fcos,
        const float* __restrict__ fsin, f16* __restrict__ Qf,
        f16* __restrict__ Kf, f16* __restrict__ Vf) {
    const int b = blockIdx.y;
    const int tile64 = blockIdx.x >> 1, jh = blockIdx.x & 1;
    const int w = threadIdx.x >> 6, lane = threadIdx.x & 63;
    const int col = lane & 15, g = lane >> 4;
    const int t = tile64 * 64 + w * 16 + col;
    const int t16 = tile64 * 4 + w;
    const size_t fbase = ((size_t)(b * NT16) + t16) * 1024;   // f16 units

    f16x8 bx[4];
    const float* xrow = x + ((size_t)(b * T_ + t)) * C_;
#pragma unroll
    for (int cc = 0; cc < 4; ++cc) {
        float4 x0 = *(const float4*)(xrow + cc * 32 + g * 8);
        float4 x1 = *(const float4*)(xrow + cc * 32 + g * 8 + 4);
        f16x8 v;
        v[0] = (f16)x0.x; v[1] = (f16)x0.y; v[2] = (f16)x0.z; v[3] = (f16)x0.w;
        v[4] = (f16)x1.x; v[5] = (f16)x1.y; v[6] = (f16)x1.z; v[7] = (f16)x1.w;
        bx[cc] = v;
    }

#pragma unroll
    for (int jj = 0; jj < 6; ++jj) {
        const int jt = jh * 6 + jj;
        f32x4 acc = {0.f, 0.f, 0.f, 0.f};
#pragma unroll
        for (int cc = 0; cc < 4; ++cc) {
            f16x8 aw = *(const f16x8*)(WT + (size_t)(jt * 16 + col) * C_ + cc * 32 + g * 8);
            acc = MFMA32(aw, bx[cc], acc);
        }
        if (jt < 8) {
            const int j3 = jt & 3;
            const int hbase = j3 * 16 + g * 4;         // head-dim base (even)
            const int i0 = hbase >> 1;
            float2 c2 = *(const float2*)(fcos + t * 32 + i0);
            float2 s2 = *(const float2*)(fsin + t * 32 + i0);
            float o0 = acc[0] * c2.x - acc[1] * s2.x;
            float o1 = acc[0] * s2.x + acc[1] * c2.x;
            float o2 = acc[2] * c2.y - acc[3] * s2.y;
            float o3 = acc[2] * s2.y + acc[3] * c2.y;
            f16x4 st; st[0] = (f16)o0; st[1] = (f16)o1; st[2] = (f16)o2; st[3] = (f16)o3;
            // fragment coords: h = hs/32, ga = (hs%32)/8, sub-off = (g&1)*4
            const int h  = j3 >> 1;
            const int ga = ((j3 & 1) << 1) + (g >> 1);
            f16* dst = (jt < 4 ? Qf : Kf) + fbase + h * 512 + (ga * 16 + col) * 8 + (g & 1) * 4;
            *(f16x4*)dst = st;
        } else {
            // V[t][d], d = (jt-8)*16 + g*4 + r  ->  [mt][(t%16/4)*16 + d%16][t%4]
            const int mt = jt - 8;
            f16* vdst = Vf + fbase + mt * 256 + ((col >> 2) * 16 + g * 4) * 4 + (col & 3);
#pragma unroll
            for (int r = 0; r < 4; ++r) vdst[r * 4] = (f16)acc[r];
        }
    }
}

// ---------------------------------------------------------------------------
// Flash attention on fragment-major inputs. Block = 4 waves (256 thr),
// grid (32,B) = 1 block/CU.  Wave w owns rows w*16 of q-tiles x AND 63-x
// (one shared kv walk; causal+pad mask applied every tile).  KVBLK=32,
// register double-buffered; __launch_bounds__(256,1) -> 256-VGPR budget.
// ---------------------------------------------------------------------------
struct Tile32 {
    f16x8 k0[2], k1[2];   // K frags, 2 sub-tiles x 2 hs-halves
    f16x4 v[2][4];        // V frags [sub][mt]
    f16x4 bi[2];          // mask bias per sub (g*4 slice)
};

__device__ __forceinline__ void load32(Tile32& t_, int it, const f16* __restrict__ kfb,
        const f16* __restrict__ vfb, const f16* __restrict__ brow, int lid, int g) {
#pragma unroll
    for (int s = 0; s < 2; ++s) {
        const f16* kt = kfb + (size_t)(it * 2 + s) * 1024;
        t_.k0[s] = *(const f16x8*)(kt + lid * 8);
        t_.k1[s] = *(const f16x8*)(kt + 512 + lid * 8);
        const f16* vt = vfb + (size_t)(it * 2 + s) * 1024;
#pragma unroll
        for (int mt = 0; mt < 4; ++mt)
            t_.v[s][mt] = *(const f16x4*)(vt + mt * 256 + lid * 4);
        t_.bi[s] = *(const f16x4*)(brow + it * 32 + s * 16 + g * 4);
    }
}

__device__ __forceinline__ void computeG(const Tile32& t_, int it, int qc, int g,
        f16x8 q0, f16x8 q1, float& m, float& lsum,
        f32x4& o0, f32x4& o1, f32x4& o2, f32x4& o3) {
    float sv[8];
#pragma unroll
    for (int s = 0; s < 2; ++s) {
        f32x4 sa = {0.f, 0.f, 0.f, 0.f};
        sa = MFMA32(t_.k0[s], q0, sa);
        sa = MFMA32(t_.k1[s], q1, sa);
        const int kbase = it * 32 + s * 16 + g * 4;
#pragma unroll
        for (int r = 0; r < 4; ++r) {
            float bb = (kbase + r <= qc) ? (float)t_.bi[s][r] : -1e30f;
            sv[s * 4 + r] = sa[r] + bb;
        }
    }
    float t0 = fmaxf(fmaxf(sv[0], sv[1]), fmaxf(sv[2], sv[3]));
    float t1 = fmaxf(fmaxf(sv[4], sv[5]), fmaxf(sv[6], sv[7]));
    float tm = fmaxf(t0, t1);
    tm = fmaxf(tm, __shfl_xor(tm, 16));
    tm = fmaxf(tm, __shfl_xor(tm, 32));
    const float mn = fmaxf(m, tm);
    const float sc = __expf(m - mn);
#pragma unroll
    for (int i = 0; i < 8; ++i) sv[i] = __expf(sv[i] - mn);
    float ts = ((sv[0] + sv[1]) + (sv[2] + sv[3])) + ((sv[4] + sv[5]) + (sv[6] + sv[7]));
    ts += __shfl_xor(ts, 16);
    ts += __shfl_xor(ts, 32);
    lsum = lsum * sc + ts;
    m = mn;
    o0 *= sc; o1 *= sc; o2 *= sc; o3 *= sc;
#pragma unroll
    for (int s = 0; s < 2; ++s) {
        f16x4 pf;
        pf[0] = (f16)sv[s * 4 + 0]; pf[1] = (f16)sv[s * 4 + 1];
        pf[2] = (f16)sv[s * 4 + 2]; pf[3] = (f16)sv[s * 4 + 3];
        o0 = MFMA16(t_.v[s][0], pf, o0);
        o1 = MFMA16(t_.v[s][1], pf, o1);
        o2 = MFMA16(t_.v[s][2], pf, o2);
        o3 = MFMA16(t_.v[s][3], pf, o3);
    }
}

__device__ __forceinline__ void writeG(float* __restrict__ out, int b, int qc, int g,
        float lsum, const f32x4& o0, const f32x4& o1, const f32x4& o2, const f32x4& o3) {
    const float inv = 1.0f / lsum;
    float* orow = out + ((size_t)(b * T_ + qc)) * HS_;
    float4 u;
    u.x = o0.x * inv; u.y = o0.y * inv; u.z = o0.z * inv; u.w = o0.w * inv;
    *(float4*)(orow + 0  + g * 4) = u;
    u.x = o1.x * inv; u.y = o1.y * inv; u.z = o1.z * inv; u.w = o1.w * inv;
    *(float4*)(orow + 16 + g * 4) = u;
    u.x = o2.x * inv; u.y = o2.y * inv; u.z = o2.z * inv; u.w = o2.w * inv;
    *(float4*)(orow + 32 + g * 4) = u;
    u.x = o3.x * inv; u.y = o3.y * inv; u.z = o3.z * inv; u.w = o3.w * inv;
    *(float4*)(orow + 48 + g * 4) = u;
}

__global__ __launch_bounds__(256, 1) void k_attn(const f16* __restrict__ Qf,
        const f16* __restrict__ Kf, const f16* __restrict__ Vf,
        const f16* __restrict__ bias, float* __restrict__ out) {
    const int b = blockIdx.y;
    const int xx = blockIdx.x;                       // 0..31
    const int w = threadIdx.x >> 6, lane = threadIdx.x & 63;
    const int col = lane & 15, g = lane >> 4;
    const int lid = g * 16 + col;
    const int tqA = xx, tqB = 63 - xx;
    const int qcA = tqA * 64 + w * 16 + col;
    const int qcB = tqB * 64 + w * 16 + col;
    const int itA = (tqA * 64 + w * 16 + 15) >> 5;   // wave-uniform
    const int itB = (tqB * 64 + w * 16 + 15) >> 5;

    const f16* qfb = Qf + (size_t)(b * NT16) * 1024;
    const f16* kfb = Kf + (size_t)(b * NT16) * 1024;
    const f16* vfb = Vf + (size_t)(b * NT16) * 1024;
    const f16* brow = bias + (size_t)b * T_;

    const f16* qA = qfb + (size_t)(tqA * 4 + w) * 1024;
    f16x8 qA0 = *(const f16x8*)(qA + lid * 8);
    f16x8 qA1 = *(const f16x8*)(qA + 512 + lid * 8);
    const f16* qB = qfb + (size_t)(tqB * 4 + w) * 1024;
    f16x8 qB0 = *(const f16x8*)(qB + lid * 8);
    f16x8 qB1 = *(const f16x8*)(qB + 512 + lid * 8);

    float mA = -3.0e38f, lA = 0.f, mB = -3.0e38f, lB = 0.f;
    f32x4 oA0 = {0,0,0,0}, oA1 = {0,0,0,0}, oA2 = {0,0,0,0}, oA3 = {0,0,0,0};
    f32x4 oB0 = {0,0,0,0}, oB1 = {0,0,0,0}, oB2 = {0,0,0,0}, oB3 = {0,0,0,0};

    Tile32 A, Bt;
    load32(A, 0, kfb, vfb, brow, lid, g);
    int it = 0;
    for (; it + 2 <= itB; it += 2) {
        load32(Bt, it + 1, kfb, vfb, brow, lid, g);
        if (it <= itA) computeG(A, it, qcA, g, qA0, qA1, mA, lA, oA0, oA1, oA2, oA3);
        computeG(A, it, qcB, g, qB0, qB1, mB, lB, oB0, oB1, oB2, oB3);
        load32(A, it + 2, kfb, vfb, brow, lid, g);
        if (it + 1 <= itA) computeG(Bt, it + 1, qcA, g, qA0, qA1, mA, lA, oA0, oA1, oA2, oA3);
        computeG(Bt, it + 1, qcB, g, qB0, qB1, mB, lB, oB0, oB1, oB2, oB3);
    }
    if (it < itB) {
        load32(Bt, it + 1, kfb, vfb, brow, lid, g);
        if (it <= itA) computeG(A, it, qcA, g, qA0, qA1, mA, lA, oA0, oA1, oA2, oA3);
        computeG(A, it, qcB, g, qB0, qB1, mB, lB, oB0, oB1, oB2, oB3);
        if (it + 1 <= itA) computeG(Bt, it + 1, qcA, g, qA0, qA1, mA, lA, oA0, oA1, oA2, oA3);
        computeG(Bt, it + 1, qcB, g, qB0, qB1, mB, lB, oB0, oB1, oB2, oB3);
    } else {
        if (it <= itA) computeG(A, it, qcA, g, qA0, qA1, mA, lA, oA0, oA1, oA2, oA3);
        computeG(A, it, qcB, g, qB0, qB1, mB, lB, oB0, oB1, oB2, oB3);
    }

    writeG(out, b, qcA, g, lA, oA0, oA1, oA2, oA3);
    writeG(out, b, qcB, g, lB, oB0, oB1, oB2, oB3);
}

// ---------------------------------------------------------------------------
extern "C" void kernel_launch(void* const* d_in, const int* in_sizes, int n_in,
                              void* d_out, int out_size, void* d_ws, size_t ws_size,
                              hipStream_t stream) {
    const float* x    = (const float*)d_in[0];
    const float* Wq   = (const float*)d_in[1];
    const float* Wk   = (const float*)d_in[2];
    const float* Wv   = (const float*)d_in[3];
    const float* fcos = (const float*)d_in[4];
    const float* fsin = (const float*)d_in[5];
    const int*   msk  = (const int*)d_in[6];

    char* ws = (char*)d_ws;
    const size_t frag_bytes = (size_t)B_ * NT16 * 2048;   // 4 MB per tensor
    f16* WT   = (f16*)ws;                                 // 48 KB
    f16* bias = (f16*)(ws + (48 << 10));                  // 64 KB
    f16* Qf   = (f16*)(ws + (1 << 17));
    f16* Kf   = (f16*)(ws + (1 << 17) + frag_bytes);
    f16* Vf   = (f16*)(ws + (1 << 17) + 2 * frag_bytes);

    k_prep<<<224, 256, 0, stream>>>(Wq, Wk, Wv, msk, WT, bias);
    dim3 g1(T_ / 32, B_);
    k_qkv<<<g1, 256, 0, stream>>>(x, WT, fcos, fsin, Qf, Kf, Vf);
    dim3 g2(32, B_);
    k_attn<<<g2, 256, 0, stream>>>(Qf, Kf, Vf, bias, (float*)d_out);
}

// Round 10
// 144.597 us; speedup vs baseline: 2.1045x; 1.1874x over previous
//
#include <hip/hip_runtime.h>

#define B_ 8
#define T_ 4096
#define C_ 128
#define HS_ 64
#define NT16 (T_ / 16)

typedef _Float16 f16;
typedef _Float16 f16x8 __attribute__((ext_vector_type(8)));
typedef _Float16 f16x4 __attribute__((ext_vector_type(4)));
typedef float f32x4 __attribute__((ext_vector_type(4)));

#define MFMA32(a, b, c) __builtin_amdgcn_mfma_f32_16x16x32_f16(a, b, c, 0, 0, 0)
#define MFMA16(a, b, c) __builtin_amdgcn_mfma_f32_16x16x16f16(a, b, c, 0, 0, 0)

// ---------------------------------------------------------------------------
// Fragment-major layouts (per [b][t16] block of 1024 f16 = 2 KB):
//  Q/K:  [h(2)][lane][8]   lane reads b128 = X[t0+col][h*32+g*8..+8]
//  V:    [mt(4)][lane][4]  lane reads b64  = V[kv0+g*4..+4][16mt+col]
// ---------------------------------------------------------------------------

__global__ void k_prep(const float* __restrict__ Wq, const float* __restrict__ Wk,
                       const float* __restrict__ Wv, const int* __restrict__ msk,
                       f16* __restrict__ WT, f16* __restrict__ bias) {
    int idx = blockIdx.x * 256 + threadIdx.x;
    if (idx < 192 * C_) {
        int j = idx >> 7, c = idx & 127;
        const float* W = (j < 64) ? Wq : (j < 128 ? Wk : Wv);
        float v = W[c * HS_ + (j & 63)];
        if (j < 64) v *= 0.08838834764831845f;     // 1/sqrt(128) folded into q
        WT[idx] = (f16)v;
    } else {
        int e = idx - 192 * C_;
        if (e < B_ * T_) bias[e] = msk[e] ? (f16)0.0f : (f16)(-30000.0f);
    }
}

// ---------------------------------------------------------------------------
// QKV projection + RoPE.  x and WT staged in swizzled LDS (coalesced global
// loads, conflict-light fragment reads); V epilogue goes through a per-wave
// swizzled LDS patch and writes back coalesced.  Grid (T/64, B) = 2 blk/CU.
// ---------------------------------------------------------------------------
__global__ __launch_bounds__(256, 2) void k_qkv(const float* __restrict__ x,
        const f16* __restrict__ WT, const float* __restrict__ fcos,
        const float* __restrict__ fsin, f16* __restrict__ Qf,
        f16* __restrict__ Kf, f16* __restrict__ Vf) {
    __shared__ f16 xs[64 * 128];        // 16 KB
    __shared__ f16 wts[192 * 128];      // 48 KB
    __shared__ f16 vst[4][4][256];      // 8 KB, per-wave V staging

    const int b = blockIdx.y;
    const int tid = threadIdx.x;
    const int w = tid >> 6, lane = tid & 63;
    const int col = lane & 15, g = lane >> 4;

    // stage x: 64 rows x 128 ch, f32 -> f16, swizzled
    const float* xb = x + ((size_t)b * T_ + (size_t)blockIdx.x * 64) * C_;
#pragma unroll
    for (int k = 0; k < 8; ++k) {
        int flat = tid * 4 + k * 1024;
        float4 v4 = *(const float4*)(xb + flat);
        f16x4 hv; hv[0] = (f16)v4.x; hv[1] = (f16)v4.y; hv[2] = (f16)v4.z; hv[3] = (f16)v4.w;
        int row = flat >> 7, chB = (flat & 127) * 2;
        int off = (row * 256 + chB) ^ ((row & 7) << 4);
        *(f16x4*)((char*)xs + off) = hv;
    }
    // stage WT: 192 rows x 128 ch f16, swizzled
#pragma unroll
    for (int k = 0; k < 12; ++k) {
        int flat = tid * 8 + k * 2048;
        f16x8 wv = *(const f16x8*)(WT + flat);
        int row = flat >> 7, chB = (flat & 127) * 2;
        int off = (row * 256 + chB) ^ ((row & 7) << 4);
        *(f16x8*)((char*)wts + off) = wv;
    }
    __syncthreads();

    const int t = blockIdx.x * 64 + w * 16 + col;
    const int t16 = blockIdx.x * 4 + w;
    const size_t fbase = ((size_t)(b * NT16) + t16) * 1024;

    f16x8 bx[4];
    {
        const int row = w * 16 + col;
#pragma unroll
        for (int cc = 0; cc < 4; ++cc) {
            int off = (row * 256 + cc * 64 + g * 16) ^ ((row & 7) << 4);
            bx[cc] = *(const f16x8*)((const char*)xs + off);
        }
    }

#pragma unroll
    for (int jt = 0; jt < 12; ++jt) {
        f32x4 acc = {0.f, 0.f, 0.f, 0.f};
        const int wrow = jt * 16 + col;
#pragma unroll
        for (int cc = 0; cc < 4; ++cc) {
            int off = (wrow * 256 + cc * 64 + g * 16) ^ ((wrow & 7) << 4);
            f16x8 aw = *(const f16x8*)((const char*)wts + off);
            acc = MFMA32(aw, bx[cc], acc);
        }
        if (jt < 8) {
            const int j3 = jt & 3;
            const int hbase = j3 * 16 + g * 4;
            const int i0 = hbase >> 1;
            float2 c2 = *(const float2*)(fcos + t * 32 + i0);
            float2 s2 = *(const float2*)(fsin + t * 32 + i0);
            float o0 = acc[0] * c2.x - acc[1] * s2.x;
            float o1 = acc[0] * s2.x + acc[1] * c2.x;
            float o2 = acc[2] * c2.y - acc[3] * s2.y;
            float o3 = acc[2] * s2.y + acc[3] * c2.y;
            f16x4 st; st[0] = (f16)o0; st[1] = (f16)o1; st[2] = (f16)o2; st[3] = (f16)o3;
            const int hh = j3 >> 1;
            const int ga = ((j3 & 1) << 1) + (g >> 1);
            f16* dst = (jt < 4 ? Qf : Kf) + fbase + hh * 512 + (ga * 16 + col) * 8 + (g & 1) * 4;
            *(f16x4*)dst = st;
        } else {
            const int mt = jt - 8;
#pragma unroll
            for (int r = 0; r < 4; ++r) {
                int F = (col >> 2) * 64 + (g * 4 + r) * 4 + (col & 3);
                int Bl = F * 2;
                Bl ^= ((Bl >> 7) & 3) << 4;
                *(f16*)((char*)&vst[w][mt][0] + Bl) = (f16)acc[r];
            }
        }
    }
    // coalesced V write-back (same-wave LDS RAW, no barrier needed)
#pragma unroll
    for (int mt = 0; mt < 4; ++mt) {
        int Bl = lane * 8;
        Bl ^= ((Bl >> 7) & 3) << 4;
        f16x4 vv = *(const f16x4*)((const char*)&vst[w][mt][0] + Bl);
        *(f16x4*)(Vf + fbase + mt * 256 + lane * 4) = vv;
    }
}

// ---------------------------------------------------------------------------
// Flash attention, split-KV halves on fragment-major inputs.
// Block = 1024 thr = 16 waves = {side(2)} x {row-group(4)} x {kv-half(2)};
// grid (32,B) = 1 block/CU -> 4 waves/SIMD, per-SIMD balanced.
// Exact defer-max (skip rescale when tile max doesn't grow); causal select
// only on the diagonal tile.  Halves merged via LDS (R8-proven pattern).
// ---------------------------------------------------------------------------
struct Tile32 {
    f16x8 k0[2], k1[2];
    f16x4 v[2][4];
    f16x4 bi[2];
};

__device__ __forceinline__ void load32(Tile32& t_, int it, const f16* __restrict__ kfb,
        const f16* __restrict__ vfb, const f16* __restrict__ brow, int lane, int g) {
#pragma unroll
    for (int s = 0; s < 2; ++s) {
        const f16* kt = kfb + (size_t)(it * 2 + s) * 1024;
        t_.k0[s] = *(const f16x8*)(kt + lane * 8);
        t_.k1[s] = *(const f16x8*)(kt + 512 + lane * 8);
        const f16* vt = vfb + (size_t)(it * 2 + s) * 1024;
#pragma unroll
        for (int mt = 0; mt < 4; ++mt)
            t_.v[s][mt] = *(const f16x4*)(vt + mt * 256 + lane * 4);
        t_.bi[s] = *(const f16x4*)(brow + it * 32 + s * 16 + g * 4);
    }
}

__device__ __forceinline__ void computeG(const Tile32& t_, int it, bool last,
        int qc, int g, f16x8 q0, f16x8 q1, float& m, float& lsum,
        f32x4& o0, f32x4& o1, f32x4& o2, f32x4& o3) {
    float sv[8];
#pragma unroll
    for (int s = 0; s < 2; ++s) {
        f32x4 sa = {0.f, 0.f, 0.f, 0.f};
        sa = MFMA32(t_.k0[s], q0, sa);
        sa = MFMA32(t_.k1[s], q1, sa);
        const int kbase = it * 32 + s * 16 + g * 4;
#pragma unroll
        for (int r = 0; r < 4; ++r) {
            float bb = (float)t_.bi[s][r];
            if (last) bb = (kbase + r <= qc) ? bb : -1e30f;
            sv[s * 4 + r] = sa[r] + bb;
        }
    }
    float t0 = fmaxf(fmaxf(sv[0], sv[1]), fmaxf(sv[2], sv[3]));
    float t1 = fmaxf(fmaxf(sv[4], sv[5]), fmaxf(sv[6], sv[7]));
    float tm = fmaxf(t0, t1);
    tm = fmaxf(tm, __shfl_xor(tm, 16));
    tm = fmaxf(tm, __shfl_xor(tm, 32));
    const bool skip = __all(tm <= m);          // exact: mn == m for every lane
    const float mn = skip ? m : fmaxf(m, tm);
#pragma unroll
    for (int i = 0; i < 8; ++i) sv[i] = __expf(sv[i] - mn);
    float ts = ((sv[0] + sv[1]) + (sv[2] + sv[3])) + ((sv[4] + sv[5]) + (sv[6] + sv[7]));
    ts += __shfl_xor(ts, 16);
    ts += __shfl_xor(ts, 32);
    if (skip) {
        lsum += ts;
    } else {
        const float sc = __expf(m - mn);
        lsum = lsum * sc + ts;
        m = mn;
        o0 *= sc; o1 *= sc; o2 *= sc; o3 *= sc;
    }
#pragma unroll
    for (int s = 0; s < 2; ++s) {
        f16x4 pf;
        pf[0] = (f16)sv[s * 4 + 0]; pf[1] = (f16)sv[s * 4 + 1];
        pf[2] = (f16)sv[s * 4 + 2]; pf[3] = (f16)sv[s * 4 + 3];
        o0 = MFMA16(t_.v[s][0], pf, o0);
        o1 = MFMA16(t_.v[s][1], pf, o1);
        o2 = MFMA16(t_.v[s][2], pf, o2);
        o3 = MFMA16(t_.v[s][3], pf, o3);
    }
}

__global__ __launch_bounds__(1024, 4) void k_attn(const f16* __restrict__ Qf,
        const f16* __restrict__ Kf, const f16* __restrict__ Vf,
        const f16* __restrict__ bias, float* __restrict__ out) {
    __shared__ float lds_o[8][64][17];
    __shared__ float lds_m[8][64];
    __shared__ float lds_l[8][64];

    const int b = blockIdx.y;
    const int xx = blockIdx.x;                 // 0..31
    const int w = threadIdx.x >> 6, lane = threadIdx.x & 63;
    const int col = lane & 15, g = lane >> 4;
    const int h = w & 1, r = (w >> 1) & 3, side = w >> 3;
    const int tq = side ? (63 - xx) : xx;
    const int qc = tq * 64 + r * 16 + col;
    const int itLast = (tq * 64 + r * 16 + 15) >> 5;   // wave-uniform
    const int LA = itLast + 1, mid = LA >> 1;
    const int start = h ? mid : 0, endEx = h ? LA : mid;
    const int slot = side * 4 + r;

    const f16* qfb = Qf + (size_t)(b * NT16) * 1024;
    const f16* kfb = Kf + (size_t)(b * NT16) * 1024;
    const f16* vfb = Vf + (size_t)(b * NT16) * 1024;
    const f16* brow = bias + (size_t)b * T_;

    const f16* qp = qfb + (size_t)(tq * 4 + r) * 1024;
    f16x8 q0 = *(const f16x8*)(qp + lane * 8);
    f16x8 q1 = *(const f16x8*)(qp + 512 + lane * 8);

    float m = -3.0e38f, lsum = 0.f;
    f32x4 o0 = {0,0,0,0}, o1 = {0,0,0,0}, o2 = {0,0,0,0}, o3 = {0,0,0,0};

    for (int it = start; it < endEx; ++it) {
        Tile32 tl;
        load32(tl, it, kfb, vfb, brow, lane, g);
        computeG(tl, it, it == itLast, qc, g, q0, q1, m, lsum, o0, o1, o2, o3);
    }

    // merge halves: h=1 publishes, h=0 combines + writes
    if (h) {
        lds_m[slot][lane] = m;
        lds_l[slot][lane] = lsum;
        float* p = lds_o[slot][lane];
        p[0] = o0.x;  p[1] = o0.y;  p[2] = o0.z;  p[3] = o0.w;
        p[4] = o1.x;  p[5] = o1.y;  p[6] = o1.z;  p[7] = o1.w;
        p[8] = o2.x;  p[9] = o2.y;  p[10] = o2.z; p[11] = o2.w;
        p[12] = o3.x; p[13] = o3.y; p[14] = o3.z; p[15] = o3.w;
    }
    __syncthreads();
    if (!h) {
        const float mB = lds_m[slot][lane];
        const float lB = lds_l[slot][lane];
        const float mn = fmaxf(m, mB);
        const float sA = __expf(m - mn), sB = __expf(mB - mn);
        const float inv = 1.0f / (lsum * sA + lB * sB);
        const float* p = lds_o[slot][lane];
        float* orow = out + ((size_t)(b * T_ + qc)) * HS_;
        float4 u;
        u.x = (o0.x * sA + p[0] * sB) * inv;  u.y = (o0.y * sA + p[1] * sB) * inv;
        u.z = (o0.z * sA + p[2] * sB) * inv;  u.w = (o0.w * sA + p[3] * sB) * inv;
        *(float4*)(orow + 0  + g * 4) = u;
        u.x = (o1.x * sA + p[4] * sB) * inv;  u.y = (o1.y * sA + p[5] * sB) * inv;
        u.z = (o1.z * sA + p[6] * sB) * inv;  u.w = (o1.w * sA + p[7] * sB) * inv;
        *(float4*)(orow + 16 + g * 4) = u;
        u.x = (o2.x * sA + p[8] * sB) * inv;  u.y = (o2.y * sA + p[9] * sB) * inv;
        u.z = (o2.z * sA + p[10] * sB) * inv; u.w = (o2.w * sA + p[11] * sB) * inv;
        *(float4*)(orow + 32 + g * 4) = u;
        u.x = (o3.x * sA + p[12] * sB) * inv; u.y = (o3.y * sA + p[13] * sB) * inv;
        u.z = (o3.z * sA + p[14] * sB) * inv; u.w = (o3.w * sA + p[15] * sB) * inv;
        *(float4*)(orow + 48 + g * 4) = u;
    }
}

// ---------------------------------------------------------------------------
extern "C" void kernel_launch(void* const* d_in, const int* in_sizes, int n_in,
                              void* d_out, int out_size, void* d_ws, size_t ws_size,
                              hipStream_t stream) {
    const float* x    = (const float*)d_in[0];
    const float* Wq   = (const float*)d_in[1];
    const float* Wk   = (const float*)d_in[2];
    const float* Wv   = (const float*)d_in[3];
    const float* fcos = (const float*)d_in[4];
    const float* fsin = (const float*)d_in[5];
    const int*   msk  = (const int*)d_in[6];

    char* ws = (char*)d_ws;
    const size_t frag_bytes = (size_t)B_ * NT16 * 2048;   // 4 MB per tensor
    f16* WT   = (f16*)ws;                                 // 48 KB
    f16* bias = (f16*)(ws + (48 << 10));                  // 64 KB
    f16* Qf   = (f16*)(ws + (1 << 17));
    f16* Kf   = (f16*)(ws + (1 << 17) + frag_bytes);
    f16* Vf   = (f16*)(ws + (1 << 17) + 2 * frag_bytes);

    k_prep<<<224, 256, 0, stream>>>(Wq, Wk, Wv, msk, WT, bias);
    dim3 g1(T_ / 64, B_);
    k_qkv<<<g1, 256, 0, stream>>>(x, WT, fcos, fsin, Qf, Kf, Vf);
    dim3 g2(32, B_);
    k_attn<<<g2, 1024, 0, stream>>>(Qf, Kf, Vf, bias, (float*)d_out);
}